// Round 1
// baseline (2143.628 us; speedup 1.0000x reference)
//
#include <hip/hip_runtime.h>
#include <hip/hip_bf16.h>

// Problem constants
#define BB 16
#define NN 512
#define DD 256
#define DA 128
#define KK 64
#define HF 1024
#define HD 1024
#define ROWS (BB * NN)            // 8192
#define ELEMS ((long long)ROWS * DD)      // 2,097,152
#define PSI_FLOATS 268435456LL    // 8192*64*512
#define PSI_F4 67108864LL

// ---------------------------------------------------------------------------
// Generic fp32 GEMM: C = act(A @ W + bias), A[M,K] row-major, W[K,N] row-major
// 64x64 tile, BK=16, 256 threads, 4x4 microtile. Batched via blockIdx.z.
// Requires M,N multiples of 64 and K multiple of 16 (true for all uses here).
// ---------------------------------------------------------------------------
template<int ACT>  // 0 = none, 1 = leaky_relu(0.01)
__global__ __launch_bounds__(256) void gemm_nn_kernel(
    const float* __restrict__ A, long long sA,
    const float* __restrict__ W, long long sW,
    const float* __restrict__ bias,
    float* __restrict__ C, long long sC,
    int M, int N, int K)
{
    const int bz = blockIdx.z;
    const float* Ab = A + (long long)bz * sA;
    const float* Wb = W + (long long)bz * sW;
    float* Cb = C + (long long)bz * sC;

    __shared__ float As[16][68];   // [k][m], stride 68 floats = 16B aligned
    __shared__ float Bs[16][68];   // [k][n]

    const int tid = threadIdx.x;
    const int bm = blockIdx.x * 64;
    const int bn = blockIdx.y * 64;
    const int tm = (tid >> 4) << 2;
    const int tn = (tid & 15) << 2;

    const int ar = tid >> 2;          // 0..63 (A row within tile)
    const int ac = (tid & 3) << 2;    // 0,4,8,12 (A col within K-tile)
    const int wr = tid >> 4;          // 0..15 (W row within K-tile)
    const int wc = (tid & 15) << 2;   // 0..60 (W col within tile)

    float acc[4][4] = {};

    for (int k0 = 0; k0 < K; k0 += 16) {
        float4 av = *reinterpret_cast<const float4*>(
            &Ab[(long long)(bm + ar) * K + k0 + ac]);
        As[ac + 0][ar] = av.x;
        As[ac + 1][ar] = av.y;
        As[ac + 2][ar] = av.z;
        As[ac + 3][ar] = av.w;
        *reinterpret_cast<float4*>(&Bs[wr][wc]) = *reinterpret_cast<const float4*>(
            &Wb[(long long)(k0 + wr) * N + bn + wc]);
        __syncthreads();
#pragma unroll
        for (int kk = 0; kk < 16; ++kk) {
            const float4 a4 = *reinterpret_cast<const float4*>(&As[kk][tm]);
            const float4 b4 = *reinterpret_cast<const float4*>(&Bs[kk][tn]);
            const float aa[4] = {a4.x, a4.y, a4.z, a4.w};
            const float bb[4] = {b4.x, b4.y, b4.z, b4.w};
#pragma unroll
            for (int i = 0; i < 4; ++i)
#pragma unroll
                for (int j = 0; j < 4; ++j)
                    acc[i][j] += aa[i] * bb[j];
        }
        __syncthreads();
    }

    float bv[4] = {0.f, 0.f, 0.f, 0.f};
    if (bias) {
#pragma unroll
        for (int j = 0; j < 4; ++j) bv[j] = bias[bn + tn + j];
    }
#pragma unroll
    for (int i = 0; i < 4; ++i) {
        float out[4];
#pragma unroll
        for (int j = 0; j < 4; ++j) {
            float r = acc[i][j] + bv[j];
            if (ACT == 1) r = (r > 0.f) ? r : 0.01f * r;
            out[j] = r;
        }
        *reinterpret_cast<float4*>(&Cb[(long long)(bm + tm + i) * N + bn + tn]) =
            make_float4(out[0], out[1], out[2], out[3]);
    }
}

// ---------------------------------------------------------------------------
// Batched NT GEMM for attention scores: C[m,n] = scale * sum_d A[m,d]*B[n,d]
// A,B: [512,128] per batch, C: [512,512] per batch.
// ---------------------------------------------------------------------------
__global__ __launch_bounds__(256) void gemm_nt_kernel(
    const float* __restrict__ A, long long sA,
    const float* __restrict__ B, long long sB,
    float* __restrict__ C, long long sC,
    int M, int N, int K, float scale)
{
    const int bz = blockIdx.z;
    const float* Ab = A + (long long)bz * sA;
    const float* Bb = B + (long long)bz * sB;
    float* Cb = C + (long long)bz * sC;

    __shared__ float As[16][68];
    __shared__ float Bs[16][68];

    const int tid = threadIdx.x;
    const int bm = blockIdx.x * 64;
    const int bn = blockIdx.y * 64;
    const int tm = (tid >> 4) << 2;
    const int tn = (tid & 15) << 2;

    const int ar = tid >> 2;
    const int ac = (tid & 3) << 2;

    float acc[4][4] = {};

    for (int k0 = 0; k0 < K; k0 += 16) {
        float4 av = *reinterpret_cast<const float4*>(
            &Ab[(long long)(bm + ar) * K + k0 + ac]);
        As[ac + 0][ar] = av.x;
        As[ac + 1][ar] = av.y;
        As[ac + 2][ar] = av.z;
        As[ac + 3][ar] = av.w;
        float4 bv = *reinterpret_cast<const float4*>(
            &Bb[(long long)(bn + ar) * K + k0 + ac]);
        Bs[ac + 0][ar] = bv.x;
        Bs[ac + 1][ar] = bv.y;
        Bs[ac + 2][ar] = bv.z;
        Bs[ac + 3][ar] = bv.w;
        __syncthreads();
#pragma unroll
        for (int kk = 0; kk < 16; ++kk) {
            const float4 a4 = *reinterpret_cast<const float4*>(&As[kk][tm]);
            const float4 b4 = *reinterpret_cast<const float4*>(&Bs[kk][tn]);
            const float aa[4] = {a4.x, a4.y, a4.z, a4.w};
            const float bb[4] = {b4.x, b4.y, b4.z, b4.w};
#pragma unroll
            for (int i = 0; i < 4; ++i)
#pragma unroll
                for (int j = 0; j < 4; ++j)
                    acc[i][j] += aa[i] * bb[j];
        }
        __syncthreads();
    }
#pragma unroll
    for (int i = 0; i < 4; ++i) {
        *reinterpret_cast<float4*>(&Cb[(long long)(bm + tm + i) * N + bn + tn]) =
            make_float4(acc[i][0] * scale, acc[i][1] * scale,
                        acc[i][2] * scale, acc[i][3] * scale);
    }
}

// ---------------------------------------------------------------------------
// Wave reductions
// ---------------------------------------------------------------------------
__device__ inline float wave_sum(float v) {
#pragma unroll
    for (int o = 32; o > 0; o >>= 1) v += __shfl_xor(v, o);
    return v;
}
__device__ inline float wave_max(float v) {
#pragma unroll
    for (int o = 32; o > 0; o >>= 1) v = fmaxf(v, __shfl_xor(v, o));
    return v;
}

// Softmax over rows of 512, in-place. One wave per row, 4 rows per block.
__global__ __launch_bounds__(256) void softmax512_kernel(float* __restrict__ S)
{
    const int lane = threadIdx.x & 63;
    const int wave = threadIdx.x >> 6;
    const long long row = (long long)blockIdx.x * 4 + wave;
    float* p = S + row * 512;

    float4 v0 = *reinterpret_cast<const float4*>(&p[lane * 4]);
    float4 v1 = *reinterpret_cast<const float4*>(&p[lane * 4 + 256]);
    float mx = fmaxf(fmaxf(fmaxf(v0.x, v0.y), fmaxf(v0.z, v0.w)),
                     fmaxf(fmaxf(v1.x, v1.y), fmaxf(v1.z, v1.w)));
    mx = wave_max(mx);
    v0.x = expf(v0.x - mx); v0.y = expf(v0.y - mx);
    v0.z = expf(v0.z - mx); v0.w = expf(v0.w - mx);
    v1.x = expf(v1.x - mx); v1.y = expf(v1.y - mx);
    v1.z = expf(v1.z - mx); v1.w = expf(v1.w - mx);
    float s = v0.x + v0.y + v0.z + v0.w + v1.x + v1.y + v1.z + v1.w;
    s = wave_sum(s);
    const float inv = 1.0f / s;
    v0.x *= inv; v0.y *= inv; v0.z *= inv; v0.w *= inv;
    v1.x *= inv; v1.y *= inv; v1.z *= inv; v1.w *= inv;
    *reinterpret_cast<float4*>(&p[lane * 4]) = v0;
    *reinterpret_cast<float4*>(&p[lane * 4 + 256]) = v1;
}

// LayerNorm(X + R) over rows of 256. One wave per row, 4 rows per block.
__global__ __launch_bounds__(256) void ln_residual_kernel(
    const float* __restrict__ X, const float* __restrict__ R,
    const float* __restrict__ g, const float* __restrict__ b,
    float* __restrict__ out)
{
    const int lane = threadIdx.x & 63;
    const int wave = threadIdx.x >> 6;
    const long long row = (long long)blockIdx.x * 4 + wave;
    const float4 xv = *reinterpret_cast<const float4*>(&X[row * 256 + lane * 4]);
    const float4 rv = *reinterpret_cast<const float4*>(&R[row * 256 + lane * 4]);
    float s0 = xv.x + rv.x, s1 = xv.y + rv.y, s2 = xv.z + rv.z, s3 = xv.w + rv.w;
    float mean = wave_sum(s0 + s1 + s2 + s3) * (1.0f / 256.0f);
    float d0 = s0 - mean, d1 = s1 - mean, d2 = s2 - mean, d3 = s3 - mean;
    float var = wave_sum(d0 * d0 + d1 * d1 + d2 * d2 + d3 * d3) * (1.0f / 256.0f);
    float inv = 1.0f / sqrtf(var + 1e-5f);
    const float4 gv = *reinterpret_cast<const float4*>(&g[lane * 4]);
    const float4 bv = *reinterpret_cast<const float4*>(&b[lane * 4]);
    float4 o;
    o.x = d0 * inv * gv.x + bv.x;
    o.y = d1 * inv * gv.y + bv.y;
    o.z = d2 * inv * gv.z + bv.z;
    o.w = d3 * inv * gv.w + bv.w;
    *reinterpret_cast<float4*>(&out[row * 256 + lane * 4]) = o;
}

// ---------------------------------------------------------------------------
// VQ: per row of zc, argmin_k ||lat - emb_k||^2, gather quant = emb[argmin].
// emb staged transposed in LDS: embT[d][k]. Lane = code index. 32 rows/block.
// ---------------------------------------------------------------------------
__global__ __launch_bounds__(256) void vq_kernel(
    const float* __restrict__ zc, const float* __restrict__ emb,
    float* __restrict__ quant)
{
    __shared__ float embT[256][64];   // 64 KiB
    const int tid = threadIdx.x;
    for (int i = tid; i < 64 * 256; i += 256) {
        const int k = i >> 8, d = i & 255;
        embT[d][k] = emb[i];
    }
    __syncthreads();

    const int lane = tid & 63;
    const int wave = tid >> 6;
    float e2 = 0.f;
#pragma unroll 8
    for (int d = 0; d < 256; ++d) { const float e = embT[d][lane]; e2 += e * e; }

    const int row0 = blockIdx.x * 32 + wave * 8;
    for (int r = row0; r < row0 + 8; ++r) {
        const float* lat = zc + (long long)r * 256;
        float dot = 0.f;
#pragma unroll 8
        for (int d = 0; d < 256; ++d) dot += lat[d] * embT[d][lane];
        float bd = e2 - 2.0f * dot;
        int bi = lane;
#pragma unroll
        for (int o = 32; o > 0; o >>= 1) {
            const float od = __shfl_xor(bd, o);
            const int oi = __shfl_xor(bi, o);
            if (od < bd || (od == bd && oi < bi)) { bd = od; bi = oi; }
        }
        const float4 qv = *reinterpret_cast<const float4*>(&emb[bi * 256 + lane * 4]);
        *reinterpret_cast<float4*>(&quant[(long long)r * 256 + lane * 4]) = qv;
    }
}

// ---------------------------------------------------------------------------
// Fused squared-diff reductions:
// acc[0] += sum (xrec-x)^2 ; acc[1] += sum (quant-zc)^2 ; acc[2] += sum (zc-zl)^2
// ---------------------------------------------------------------------------
__global__ __launch_bounds__(256) void loss_reduce_kernel(
    const float* __restrict__ xrec, const float* __restrict__ x,
    const float* __restrict__ quant, const float* __restrict__ zc,
    const float* __restrict__ zl, float* __restrict__ acc)
{
    const long long n4 = ELEMS / 4;   // 524288
    const long long stride = (long long)gridDim.x * blockDim.x;
    float s0 = 0.f, s1 = 0.f, s2 = 0.f;
    for (long long i = (long long)blockIdx.x * blockDim.x + threadIdx.x;
         i < n4; i += stride) {
        const float4 a = reinterpret_cast<const float4*>(xrec)[i];
        const float4 b = reinterpret_cast<const float4*>(x)[i];
        const float4 q = reinterpret_cast<const float4*>(quant)[i];
        const float4 c = reinterpret_cast<const float4*>(zc)[i];
        const float4 l = reinterpret_cast<const float4*>(zl)[i];
        float d;
        d = a.x - b.x; s0 += d * d; d = a.y - b.y; s0 += d * d;
        d = a.z - b.z; s0 += d * d; d = a.w - b.w; s0 += d * d;
        d = q.x - c.x; s1 += d * d; d = q.y - c.y; s1 += d * d;
        d = q.z - c.z; s1 += d * d; d = q.w - c.w; s1 += d * d;
        d = c.x - l.x; s2 += d * d; d = c.y - l.y; s2 += d * d;
        d = c.z - l.z; s2 += d * d; d = c.w - l.w; s2 += d * d;
    }
    s0 = wave_sum(s0); s1 = wave_sum(s1); s2 = wave_sum(s2);
    if ((threadIdx.x & 63) == 0) {
        atomicAdd(&acc[0], s0);
        atomicAdd(&acc[1], s1);
        atomicAdd(&acc[2], s2);
    }
}

__global__ void finalize_loss_kernel(const float* __restrict__ acc,
                                     float* __restrict__ out)
{
    if (threadIdx.x == 0) {
        // loss = recon + 1.25*mean((quant-lat)^2) + infer  (all means over ELEMS)
        out[0] = (acc[0] + 1.25f * acc[1] + acc[2]) * (1.0f / (float)ELEMS);
    }
}

// ---------------------------------------------------------------------------
// psi_hid fill: out[(bn*64 + k)*512 + c] = c<256 ? zc[bn,c] : emb[k,c-256]
// float4 grid-stride; writes fully coalesced. 1 GiB of writes -> HBM-bound.
// ---------------------------------------------------------------------------
__global__ __launch_bounds__(256) void psi_fill_kernel(
    const float* __restrict__ zc, const float* __restrict__ emb,
    float4* __restrict__ out)
{
    const long long stride = (long long)gridDim.x * blockDim.x;
    for (long long i = (long long)blockIdx.x * blockDim.x + threadIdx.x;
         i < PSI_F4; i += stride) {
        const int row = (int)(i >> 7);       // / 128 float4s per 512-row
        const int c4 = (int)(i & 127);
        const int bn = row >> 6;
        const int k = row & 63;
        float4 v;
        if (c4 < 64) v = *reinterpret_cast<const float4*>(&zc[bn * 256 + c4 * 4]);
        else v = *reinterpret_cast<const float4*>(&emb[k * 256 + (c4 - 64) * 4]);
        out[i] = v;
    }
}

// ---------------------------------------------------------------------------
// Host launcher
// ---------------------------------------------------------------------------
extern "C" void kernel_launch(void* const* d_in, const int* in_sizes, int n_in,
                              void* d_out, int out_size, void* d_ws, size_t ws_size,
                              hipStream_t stream)
{
    const float* x      = (const float*)d_in[0];
    const float* Wq_w   = (const float*)d_in[1];
    const float* Wq_b   = (const float*)d_in[2];
    const float* Wk_w   = (const float*)d_in[3];
    const float* Wk_b   = (const float*)d_in[4];
    const float* Wv_w   = (const float*)d_in[5];
    const float* Wv_b   = (const float*)d_in[6];
    const float* ln1_g  = (const float*)d_in[7];
    const float* ln1_b  = (const float*)d_in[8];
    const float* ln2_g  = (const float*)d_in[9];
    const float* ln2_b  = (const float*)d_in[10];
    const float* ffn_w1 = (const float*)d_in[11];
    const float* ffn_b1 = (const float*)d_in[12];
    const float* ffn_w2 = (const float*)d_in[13];
    const float* ffn_b2 = (const float*)d_in[14];
    const float* emb    = (const float*)d_in[15];
    const float* dec_w1 = (const float*)d_in[16];
    const float* dec_b1 = (const float*)d_in[17];
    const float* dec_w2 = (const float*)d_in[18];
    const float* dec_b2 = (const float*)d_in[19];
    const float* dec_w3 = (const float*)d_in[20];
    const float* dec_b3 = (const float*)d_in[21];
    const float* li_w1  = (const float*)d_in[22];
    const float* li_b1  = (const float*)d_in[23];
    const float* li_w2  = (const float*)d_in[24];
    const float* li_b2  = (const float*)d_in[25];

    float* ws = (float*)d_ws;
    // workspace layout (float offsets)
    float* q     = ws + 0;              //  1,048,576  [8192,128]
    float* kbuf  = ws + 1048576;        //  1,048,576  [8192,128]
    float* v     = ws + 2097152;        //  2,097,152  [8192,256] -> reused z_local
    float* score = ws + 4194304;        //  4,194,304  [16,512,512]
    float* attn  = ws + 8388608;        //  2,097,152  -> reused ffn_out, x_recon
    float* z     = ws + 10485760;       //  2,097,152
    float* zc    = ws + 12582912;       //  2,097,152
    float* quant = ws + 14680064;       //  2,097,152
    float* hA    = ws + 16777216;       //  8,388,608  [8192,1024] ffn_h/li_h/dec_h1
    float* hB    = ws + 25165824;       //  8,388,608  dec_h2
    float* acc   = ws + 33554432;       //  3 floats
    // total ~134.2 MB

    float* out = (float*)d_out;
    float* loss_out = out + PSI_FLOATS;

    hipMemsetAsync(acc, 0, 4 * sizeof(float), stream);

    const float scale = 0.08838834764831843f;  // 1/sqrt(128)

    // q, k, v projections
    gemm_nn_kernel<0><<<dim3(128, 2, 1), 256, 0, stream>>>(
        x, 0, Wq_w, 0, Wq_b, q, 0, ROWS, DA, DD);
    gemm_nn_kernel<0><<<dim3(128, 2, 1), 256, 0, stream>>>(
        x, 0, Wk_w, 0, Wk_b, kbuf, 0, ROWS, DA, DD);
    gemm_nn_kernel<0><<<dim3(128, 4, 1), 256, 0, stream>>>(
        x, 0, Wv_w, 0, Wv_b, v, 0, ROWS, DD, DD);

    // scores = softmax(q @ k^T / sqrt(DA))
    gemm_nt_kernel<<<dim3(8, 8, BB), 256, 0, stream>>>(
        q, (long long)NN * DA, kbuf, (long long)NN * DA,
        score, (long long)NN * NN, NN, NN, DA, scale);
    softmax512_kernel<<<2048, 256, 0, stream>>>(score);

    // attn = score @ v
    gemm_nn_kernel<0><<<dim3(8, 4, BB), 256, 0, stream>>>(
        score, (long long)NN * NN, v, (long long)NN * DD, nullptr,
        attn, (long long)NN * DD, NN, DD, NN);

    // z = LN(x + attn)
    ln_residual_kernel<<<2048, 256, 0, stream>>>(x, attn, ln1_g, ln1_b, z);

    // ffn
    gemm_nn_kernel<1><<<dim3(128, 16, 1), 256, 0, stream>>>(
        z, 0, ffn_w1, 0, ffn_b1, hA, 0, ROWS, HF, DD);
    gemm_nn_kernel<0><<<dim3(128, 4, 1), 256, 0, stream>>>(
        hA, 0, ffn_w2, 0, ffn_b2, attn /*ffn_out*/, 0, ROWS, DD, HF);

    // z_coor = LN(z + ffn_out)
    ln_residual_kernel<<<2048, 256, 0, stream>>>(z, attn, ln2_g, ln2_b, zc);

    // local inference head: z_local (into v buffer, v no longer needed)
    gemm_nn_kernel<1><<<dim3(128, 16, 1), 256, 0, stream>>>(
        x, 0, li_w1, 0, li_b1, hA, 0, ROWS, HD, DD);
    gemm_nn_kernel<0><<<dim3(128, 4, 1), 256, 0, stream>>>(
        hA, 0, li_w2, 0, li_b2, v /*z_local*/, 0, ROWS, DD, HD);

    // VQ quantize
    vq_kernel<<<256, 256, 0, stream>>>(zc, emb, quant);

    // decoder (x_recon into attn buffer)
    gemm_nn_kernel<1><<<dim3(128, 16, 1), 256, 0, stream>>>(
        quant, 0, dec_w1, 0, dec_b1, hA, 0, ROWS, HD, DD);
    gemm_nn_kernel<1><<<dim3(128, 16, 1), 256, 0, stream>>>(
        hA, 0, dec_w2, 0, dec_b2, hB, 0, ROWS, HD, HD);
    gemm_nn_kernel<0><<<dim3(128, 4, 1), 256, 0, stream>>>(
        hB, 0, dec_w3, 0, dec_b3, attn /*x_recon*/, 0, ROWS, DD, HD);

    // losses
    loss_reduce_kernel<<<1024, 256, 0, stream>>>(attn, x, quant, zc, v, acc);
    finalize_loss_kernel<<<1, 64, 0, stream>>>(acc, loss_out);

    // psi_hid
    psi_fill_kernel<<<2048, 256, 0, stream>>>(zc, emb, (float4*)out);
}

// Round 3
// 1690.674 us; speedup vs baseline: 1.2679x; 1.2679x over previous
//
#include <hip/hip_runtime.h>
#include <hip/hip_bf16.h>

// Problem constants
#define BB 16
#define NN 512
#define DD 256
#define DAq 128
#define KK 64
#define HF 1024
#define HD 1024
#define ROWS (BB * NN)                 // 8192
#define ELEMS ((long long)ROWS * DD)   // 2,097,152
#define PSI_FLOATS 268435456LL
#define PSI_F4 67108864LL

typedef short bf16x8 __attribute__((ext_vector_type(8)));
typedef float f32x4 __attribute__((ext_vector_type(4)));

// ---- bf16 helpers (RNE, bit-level; avoids HIP type API differences) ----
__device__ inline unsigned short f2bf(float f) {
    unsigned int u = __float_as_uint(f);
    unsigned int r = (u + 0x7fffu + ((u >> 16) & 1u)) >> 16;
    return (unsigned short)r;
}
__device__ inline float bf2f(unsigned short s) {
    return __uint_as_float(((unsigned int)s) << 16);
}

__device__ inline float wave_sum(float v) {
#pragma unroll
    for (int o = 32; o > 0; o >>= 1) v += __shfl_xor(v, o);
    return v;
}
__device__ inline double wave_sum_d(double v) {
#pragma unroll
    for (int o = 32; o > 0; o >>= 1) v += __shfl_xor(v, o);
    return v;
}
__device__ inline float wave_max(float v) {
#pragma unroll
    for (int o = 32; o > 0; o >>= 1) v = fmaxf(v, __shfl_xor(v, o));
    return v;
}

// ---------------------------------------------------------------------------
// MFMA GEMM. A: [M,K] bf16 row-major (hi[,lo]). B: [N,K] bf16 row-major
// (pre-transposed weights / NT activations). C = act(scale*A@B^T_layout + bias).
// BM x 128 tile, 4 waves (2x2), BK=32, mfma_f32_16x16x32_bf16.
// SPLIT: A/B have hi+lo planes -> 3 mfmas/K-step (fp32-quality).
// OUT: 0 = fp32, 1 = bf16, 2 = bf16 hi+lo pair.
// ---------------------------------------------------------------------------
template<int BM, int SPLIT, int ACT, int OUT>
__global__ __launch_bounds__(256) void gemm_mfma(
    const ushort* __restrict__ Ah, const ushort* __restrict__ Al,
    long long sA, int ldA,
    const ushort* __restrict__ Bh, const ushort* __restrict__ Bl,
    long long sB, int ldB,
    const float* __restrict__ bias,
    void* __restrict__ Cp, void* __restrict__ C2p,
    long long sC, int ldC,
    int K, float scale)
{
    constexpr int MF = BM / 32;   // M-fragments per wave (wave covers BM/2 rows)
    const int bz = blockIdx.z;
    const ushort* A0 = Ah + bz * sA;
    const ushort* A1 = SPLIT ? (Al + bz * sA) : nullptr;
    const ushort* B0 = Bh + bz * sB;
    const ushort* B1 = SPLIT ? (Bl + bz * sB) : nullptr;

    __shared__ __align__(16) ushort As[SPLIT + 1][BM][40];
    __shared__ __align__(16) ushort Bs[SPLIT + 1][128][40];

    const int tid = threadIdx.x;
    const int lane = tid & 63;
    const int wid = tid >> 6;
    const int bm = blockIdx.x * BM;
    const int bn = blockIdx.y * 128;
    const int wm = (wid >> 1) * (BM / 2);
    const int wn = (wid & 1) * 64;
    const int fr = lane & 15;
    const int kg = lane >> 4;

    f32x4 acc[MF][4] = {};

    for (int k0 = 0; k0 < K; k0 += 32) {
        for (int idx = tid; idx < BM * 4; idx += 256) {
            const int row = idx >> 2, c = (idx & 3) * 8;
            *reinterpret_cast<uint4*>(&As[0][row][c]) =
                *reinterpret_cast<const uint4*>(&A0[(long long)(bm + row) * ldA + k0 + c]);
            if (SPLIT)
                *reinterpret_cast<uint4*>(&As[1][row][c]) =
                    *reinterpret_cast<const uint4*>(&A1[(long long)(bm + row) * ldA + k0 + c]);
        }
        for (int idx = tid; idx < 512; idx += 256) {
            const int row = idx >> 2, c = (idx & 3) * 8;
            *reinterpret_cast<uint4*>(&Bs[0][row][c]) =
                *reinterpret_cast<const uint4*>(&B0[(long long)(bn + row) * ldB + k0 + c]);
            if (SPLIT)
                *reinterpret_cast<uint4*>(&Bs[1][row][c]) =
                    *reinterpret_cast<const uint4*>(&B1[(long long)(bn + row) * ldB + k0 + c]);
        }
        __syncthreads();

        bf16x8 a0[MF], a1[MF], b0[4], b1[4];
#pragma unroll
        for (int m = 0; m < MF; ++m) {
            a0[m] = *reinterpret_cast<const bf16x8*>(&As[0][wm + m * 16 + fr][kg * 8]);
            if (SPLIT)
                a1[m] = *reinterpret_cast<const bf16x8*>(&As[1][wm + m * 16 + fr][kg * 8]);
        }
#pragma unroll
        for (int n = 0; n < 4; ++n) {
            b0[n] = *reinterpret_cast<const bf16x8*>(&Bs[0][wn + n * 16 + fr][kg * 8]);
            if (SPLIT)
                b1[n] = *reinterpret_cast<const bf16x8*>(&Bs[1][wn + n * 16 + fr][kg * 8]);
        }
#pragma unroll
        for (int m = 0; m < MF; ++m)
#pragma unroll
            for (int n = 0; n < 4; ++n) {
                acc[m][n] = __builtin_amdgcn_mfma_f32_16x16x32_bf16(a0[m], b0[n], acc[m][n], 0, 0, 0);
                if (SPLIT) {
                    acc[m][n] = __builtin_amdgcn_mfma_f32_16x16x32_bf16(a0[m], b1[n], acc[m][n], 0, 0, 0);
                    acc[m][n] = __builtin_amdgcn_mfma_f32_16x16x32_bf16(a1[m], b0[n], acc[m][n], 0, 0, 0);
                }
            }
        __syncthreads();
    }

    // epilogue: C/D mapping col = lane&15, row = (lane>>4)*4 + r  [m89-verified]
#pragma unroll
    for (int m = 0; m < MF; ++m) {
        const int row = bm + wm + m * 16 + kg * 4;
#pragma unroll
        for (int n = 0; n < 4; ++n) {
            const int col = bn + wn + n * 16 + fr;
            const float bv = bias ? bias[col] : 0.0f;
#pragma unroll
            for (int r = 0; r < 4; ++r) {
                float v = acc[m][n][r] * scale + bv;
                if (ACT) v = (v > 0.f) ? v : 0.01f * v;
                const long long off = bz * sC + (long long)(row + r) * ldC + col;
                if (OUT == 0) {
                    ((float*)Cp)[off] = v;
                } else if (OUT == 1) {
                    ((ushort*)Cp)[off] = f2bf(v);
                } else {
                    const unsigned short h = f2bf(v);
                    ((ushort*)Cp)[off] = h;
                    ((ushort*)C2p)[off] = f2bf(v - bf2f(h));
                }
            }
        }
    }
}

// ---------------------------------------------------------------------------
// fp32 [K,N] weight -> bf16 [N,K] transpose (+ optional lo plane), row offset
// for concatenating Wq/Wk/Wv into one [512,256] operand.
// ---------------------------------------------------------------------------
template<int SPLIT>
__global__ __launch_bounds__(256) void wtrans_kernel(
    const float* __restrict__ W, int Krows, int Ncols,
    ushort* __restrict__ Th, ushort* __restrict__ Tl, int rowOff, int ldT)
{
    __shared__ float t[32][33];
    const int n0 = blockIdx.x * 32, k0 = blockIdx.y * 32;
    const int r = threadIdx.x >> 5, c = threadIdx.x & 31;
#pragma unroll
    for (int i = 0; i < 4; ++i)
        t[r + i * 8][c] = W[(long long)(k0 + r + i * 8) * Ncols + n0 + c];
    __syncthreads();
#pragma unroll
    for (int i = 0; i < 4; ++i) {
        const int a = r + i * 8;
        const float v = t[c][a];          // = W[k0+c][n0+a]
        const long long o = (long long)(n0 + a + rowOff) * ldT + k0 + c;
        const unsigned short h = f2bf(v);
        Th[o] = h;
        if (SPLIT) Tl[o] = f2bf(v - bf2f(h));
    }
}

// Batched bf16 transpose of the v slice: qkv[:, 256:512] -> vT[16][256][512].
__global__ __launch_bounds__(256) void vtrans_kernel(
    const ushort* __restrict__ Vh, const ushort* __restrict__ Vl,
    ushort* __restrict__ Th, ushort* __restrict__ Tl)
{
    __shared__ ushort t[32][34];
    const int b = blockIdx.z;
    const int n0 = blockIdx.x * 32;
    const int d0 = blockIdx.y * 32;
    const int r = threadIdx.x >> 5, c = threadIdx.x & 31;
#pragma unroll
    for (int pass = 0; pass < 2; ++pass) {
        const ushort* src = pass ? Vl : Vh;
        ushort* dst = pass ? Tl : Th;
#pragma unroll
        for (int i = 0; i < 4; ++i)
            t[r + i * 8][c] = src[(long long)(b * 512 + n0 + r + i * 8) * 512 + 256 + d0 + c];
        __syncthreads();
#pragma unroll
        for (int i = 0; i < 4; ++i) {
            const int a = r + i * 8;
            dst[(long long)b * 131072 + (long long)(d0 + a) * 512 + n0 + c] = t[c][a];
        }
        __syncthreads();
    }
}

// x -> hi/lo bf16 planes
__global__ __launch_bounds__(256) void xsplit_kernel(
    const float* __restrict__ x, ushort* __restrict__ xh, ushort* __restrict__ xl)
{
    const long long n4 = ELEMS / 4;
    const long long stride = (long long)gridDim.x * blockDim.x;
    for (long long i = (long long)blockIdx.x * blockDim.x + threadIdx.x; i < n4; i += stride) {
        const float4 v = reinterpret_cast<const float4*>(x)[i];
        ushort4 h, l;
        h.x = f2bf(v.x); l.x = f2bf(v.x - bf2f(h.x));
        h.y = f2bf(v.y); l.y = f2bf(v.y - bf2f(h.y));
        h.z = f2bf(v.z); l.z = f2bf(v.z - bf2f(h.z));
        h.w = f2bf(v.w); l.w = f2bf(v.w - bf2f(h.w));
        reinterpret_cast<ushort4*>(xh)[i] = h;
        reinterpret_cast<ushort4*>(xl)[i] = l;
    }
}

__global__ void bias_concat_kernel(const float* __restrict__ qb,
                                   const float* __restrict__ kb,
                                   const float* __restrict__ vb,
                                   float* __restrict__ o)
{
    const int i = threadIdx.x;   // 512 threads
    o[i] = (i < 128) ? qb[i] : (i < 256) ? kb[i - 128] : vb[i - 256];
}

// Softmax over rows of 512 -> bf16 hi/lo planes. One wave per row.
__global__ __launch_bounds__(256) void softmax_split_kernel(
    const float* __restrict__ S, ushort* __restrict__ Ph, ushort* __restrict__ Pl)
{
    const int lane = threadIdx.x & 63;
    const long long row = (long long)blockIdx.x * 4 + (threadIdx.x >> 6);
    const float* p = S + row * 512;
    float4 v0 = *reinterpret_cast<const float4*>(&p[lane * 4]);
    float4 v1 = *reinterpret_cast<const float4*>(&p[lane * 4 + 256]);
    float mx = fmaxf(fmaxf(fmaxf(v0.x, v0.y), fmaxf(v0.z, v0.w)),
                     fmaxf(fmaxf(v1.x, v1.y), fmaxf(v1.z, v1.w)));
    mx = wave_max(mx);
    v0.x = expf(v0.x - mx); v0.y = expf(v0.y - mx);
    v0.z = expf(v0.z - mx); v0.w = expf(v0.w - mx);
    v1.x = expf(v1.x - mx); v1.y = expf(v1.y - mx);
    v1.z = expf(v1.z - mx); v1.w = expf(v1.w - mx);
    float s = wave_sum(v0.x + v0.y + v0.z + v0.w + v1.x + v1.y + v1.z + v1.w);
    const float inv = 1.0f / s;
    ushort4 h, l;
    float e;
    e = v0.x * inv; h.x = f2bf(e); l.x = f2bf(e - bf2f(h.x));
    e = v0.y * inv; h.y = f2bf(e); l.y = f2bf(e - bf2f(h.y));
    e = v0.z * inv; h.z = f2bf(e); l.z = f2bf(e - bf2f(h.z));
    e = v0.w * inv; h.w = f2bf(e); l.w = f2bf(e - bf2f(h.w));
    *reinterpret_cast<ushort4*>(&Ph[row * 512 + lane * 4]) = h;
    *reinterpret_cast<ushort4*>(&Pl[row * 512 + lane * 4]) = l;
    e = v1.x * inv; h.x = f2bf(e); l.x = f2bf(e - bf2f(h.x));
    e = v1.y * inv; h.y = f2bf(e); l.y = f2bf(e - bf2f(h.y));
    e = v1.z * inv; h.z = f2bf(e); l.z = f2bf(e - bf2f(h.z));
    e = v1.w * inv; h.w = f2bf(e); l.w = f2bf(e - bf2f(h.w));
    *reinterpret_cast<ushort4*>(&Ph[row * 512 + lane * 4 + 256]) = h;
    *reinterpret_cast<ushort4*>(&Pl[row * 512 + lane * 4 + 256]) = l;
}

// LN(X+R): fp32 out + optional bf16 hi/lo planes. One wave per 256-col row.
template<int SPLIT>
__global__ __launch_bounds__(256) void ln_kernel(
    const float* __restrict__ X, const float* __restrict__ R,
    const float* __restrict__ g, const float* __restrict__ b,
    float* __restrict__ out, ushort* __restrict__ oh, ushort* __restrict__ ol)
{
    const int lane = threadIdx.x & 63;
    const long long row = (long long)blockIdx.x * 4 + (threadIdx.x >> 6);
    const float4 xv = *reinterpret_cast<const float4*>(&X[row * 256 + lane * 4]);
    const float4 rv = *reinterpret_cast<const float4*>(&R[row * 256 + lane * 4]);
    float s0 = xv.x + rv.x, s1 = xv.y + rv.y, s2 = xv.z + rv.z, s3 = xv.w + rv.w;
    const float mean = wave_sum(s0 + s1 + s2 + s3) * (1.0f / 256.0f);
    const float d0 = s0 - mean, d1 = s1 - mean, d2 = s2 - mean, d3 = s3 - mean;
    const float var = wave_sum(d0 * d0 + d1 * d1 + d2 * d2 + d3 * d3) * (1.0f / 256.0f);
    const float inv = 1.0f / sqrtf(var + 1e-5f);
    const float4 gv = *reinterpret_cast<const float4*>(&g[lane * 4]);
    const float4 bv = *reinterpret_cast<const float4*>(&b[lane * 4]);
    float4 o;
    o.x = d0 * inv * gv.x + bv.x;
    o.y = d1 * inv * gv.y + bv.y;
    o.z = d2 * inv * gv.z + bv.z;
    o.w = d3 * inv * gv.w + bv.w;
    *reinterpret_cast<float4*>(&out[row * 256 + lane * 4]) = o;
    if (SPLIT) {
        ushort4 h, l;
        h.x = f2bf(o.x); l.x = f2bf(o.x - bf2f(h.x));
        h.y = f2bf(o.y); l.y = f2bf(o.y - bf2f(h.y));
        h.z = f2bf(o.z); l.z = f2bf(o.z - bf2f(h.z));
        h.w = f2bf(o.w); l.w = f2bf(o.w - bf2f(h.w));
        *reinterpret_cast<ushort4*>(&oh[row * 256 + lane * 4]) = h;
        *reinterpret_cast<ushort4*>(&ol[row * 256 + lane * 4]) = l;
    }
}

// VQ argmin + gather; also emit bf16 copy of quant for the decoder.
__global__ __launch_bounds__(256) void vq_kernel(
    const float* __restrict__ zc, const float* __restrict__ emb,
    float* __restrict__ quant, ushort* __restrict__ quantb)
{
    __shared__ float embT[256][64];
    const int tid = threadIdx.x;
    for (int i = tid; i < 64 * 256; i += 256) {
        const int k = i >> 8, d = i & 255;
        embT[d][k] = emb[i];
    }
    __syncthreads();

    const int lane = tid & 63;
    const int wave = tid >> 6;
    float e2 = 0.f;
#pragma unroll 8
    for (int d = 0; d < 256; ++d) { const float e = embT[d][lane]; e2 += e * e; }

    const int row0 = blockIdx.x * 32 + wave * 8;
    for (int r = row0; r < row0 + 8; ++r) {
        const float* lat = zc + (long long)r * 256;
        float dot = 0.f;
#pragma unroll 8
        for (int d = 0; d < 256; ++d) dot += lat[d] * embT[d][lane];
        float bd = e2 - 2.0f * dot;
        int bi = lane;
#pragma unroll
        for (int o = 32; o > 0; o >>= 1) {
            const float od = __shfl_xor(bd, o);
            const int oi = __shfl_xor(bi, o);
            if (od < bd || (od == bd && oi < bi)) { bd = od; bi = oi; }
        }
        const float4 qv = *reinterpret_cast<const float4*>(&emb[bi * 256 + lane * 4]);
        *reinterpret_cast<float4*>(&quant[(long long)r * 256 + lane * 4]) = qv;
        ushort4 qb;
        qb.x = f2bf(qv.x); qb.y = f2bf(qv.y); qb.z = f2bf(qv.z); qb.w = f2bf(qv.w);
        *reinterpret_cast<ushort4*>(&quantb[(long long)r * 256 + lane * 4]) = qb;
    }
}

// fp64-accumulated fused loss reductions.
__global__ __launch_bounds__(256) void loss_reduce_kernel(
    const float* __restrict__ xrec, const float* __restrict__ x,
    const float* __restrict__ quant, const float* __restrict__ zc,
    const float* __restrict__ zl, double* __restrict__ acc)
{
    const long long n4 = ELEMS / 4;
    const long long stride = (long long)gridDim.x * blockDim.x;
    double s0 = 0., s1 = 0., s2 = 0.;
    for (long long i = (long long)blockIdx.x * blockDim.x + threadIdx.x;
         i < n4; i += stride) {
        const float4 a = reinterpret_cast<const float4*>(xrec)[i];
        const float4 b = reinterpret_cast<const float4*>(x)[i];
        const float4 q = reinterpret_cast<const float4*>(quant)[i];
        const float4 c = reinterpret_cast<const float4*>(zc)[i];
        const float4 l = reinterpret_cast<const float4*>(zl)[i];
        float d;
        float t0 = 0.f, t1 = 0.f, t2 = 0.f;
        d = a.x - b.x; t0 += d * d; d = a.y - b.y; t0 += d * d;
        d = a.z - b.z; t0 += d * d; d = a.w - b.w; t0 += d * d;
        d = q.x - c.x; t1 += d * d; d = q.y - c.y; t1 += d * d;
        d = q.z - c.z; t1 += d * d; d = q.w - c.w; t1 += d * d;
        d = c.x - l.x; t2 += d * d; d = c.y - l.y; t2 += d * d;
        d = c.z - l.z; t2 += d * d; d = c.w - l.w; t2 += d * d;
        s0 += t0; s1 += t1; s2 += t2;
    }
    s0 = wave_sum_d(s0); s1 = wave_sum_d(s1); s2 = wave_sum_d(s2);
    if ((threadIdx.x & 63) == 0) {
        atomicAdd(&acc[0], s0);
        atomicAdd(&acc[1], s1);
        atomicAdd(&acc[2], s2);
    }
}

__global__ void finalize_loss_kernel(const double* __restrict__ acc,
                                     float* __restrict__ out)
{
    if (threadIdx.x == 0)
        out[0] = (float)((acc[0] + 1.25 * acc[1] + acc[2]) / (double)ELEMS);
}

// psi_hid fill (1 GiB coalesced float4 writes; HBM-bound floor).
__global__ __launch_bounds__(256) void psi_fill_kernel(
    const float* __restrict__ zc, const float* __restrict__ emb,
    float4* __restrict__ out)
{
    const long long stride = (long long)gridDim.x * blockDim.x;
    for (long long i = (long long)blockIdx.x * blockDim.x + threadIdx.x;
         i < PSI_F4; i += stride) {
        const int row = (int)(i >> 7);
        const int c4 = (int)(i & 127);
        const int bn = row >> 6;
        const int k = row & 63;
        float4 v;
        if (c4 < 64) v = *reinterpret_cast<const float4*>(&zc[bn * 256 + c4 * 4]);
        else v = *reinterpret_cast<const float4*>(&emb[k * 256 + (c4 - 64) * 4]);
        out[i] = v;
    }
}

// ---------------------------------------------------------------------------
extern "C" void kernel_launch(void* const* d_in, const int* in_sizes, int n_in,
                              void* d_out, int out_size, void* d_ws, size_t ws_size,
                              hipStream_t stream)
{
    const float* x      = (const float*)d_in[0];
    const float* Wq_w   = (const float*)d_in[1];
    const float* Wq_b   = (const float*)d_in[2];
    const float* Wk_w   = (const float*)d_in[3];
    const float* Wk_b   = (const float*)d_in[4];
    const float* Wv_w   = (const float*)d_in[5];
    const float* Wv_b   = (const float*)d_in[6];
    const float* ln1_g  = (const float*)d_in[7];
    const float* ln1_b  = (const float*)d_in[8];
    const float* ln2_g  = (const float*)d_in[9];
    const float* ln2_b  = (const float*)d_in[10];
    const float* ffn_w1 = (const float*)d_in[11];
    const float* ffn_b1 = (const float*)d_in[12];
    const float* ffn_w2 = (const float*)d_in[13];
    const float* ffn_b2 = (const float*)d_in[14];
    const float* emb    = (const float*)d_in[15];
    const float* dec_w1 = (const float*)d_in[16];
    const float* dec_b1 = (const float*)d_in[17];
    const float* dec_w2 = (const float*)d_in[18];
    const float* dec_b2 = (const float*)d_in[19];
    const float* dec_w3 = (const float*)d_in[20];
    const float* dec_b3 = (const float*)d_in[21];
    const float* li_w1  = (const float*)d_in[22];
    const float* li_b1  = (const float*)d_in[23];
    const float* li_w2  = (const float*)d_in[24];
    const float* li_b2  = (const float*)d_in[25];

    char* wsb = (char*)d_ws;
    size_t off = 0;
    auto alloc = [&](size_t bytes) {
        void* p = wsb + off;
        off += (bytes + 255) & ~(size_t)255;
        return p;
    };
    ushort* xh      = (ushort*)alloc(4194304);
    ushort* xl      = (ushort*)alloc(4194304);
    ushort* wqkvTh  = (ushort*)alloc(262144);
    ushort* wqkvTl  = (ushort*)alloc(262144);
    ushort* fw1Th   = (ushort*)alloc(524288);
    ushort* fw1Tl   = (ushort*)alloc(524288);
    ushort* fw2Th   = (ushort*)alloc(524288);
    ushort* fw2Tl   = (ushort*)alloc(524288);
    ushort* liw1T   = (ushort*)alloc(524288);
    ushort* liw2T   = (ushort*)alloc(524288);
    ushort* decw1T  = (ushort*)alloc(524288);
    ushort* decw2T  = (ushort*)alloc(2097152);
    ushort* decw3T  = (ushort*)alloc(524288);
    float*  qkvbias = (float*)alloc(2048);
    ushort* qkvh    = (ushort*)alloc(8388608);   // later: softmax hi plane
    ushort* qkvl    = (ushort*)alloc(8388608);   // later: softmax lo plane
    ushort* vTh     = (ushort*)alloc(4194304);   // later (with vTl): z_local fp32
    ushort* vTl     = (ushort*)alloc(4194304);
    float*  score   = (float*)alloc(16777216);   // later: hff_h, h1b, g1b
    ushort* hffl    = (ushort*)alloc(16777216);  // later: g2b
    float*  attn    = (float*)alloc(8388608);    // later: ffn_out, x_recon
    float*  zbuf    = (float*)alloc(8388608);    // later: quant fp32
    ushort* zh      = (ushort*)alloc(4194304);   // later: quant bf16
    ushort* zl      = (ushort*)alloc(4194304);
    float*  zc      = (float*)alloc(8388608);
    double* accd    = (double*)alloc(256);

    // aliases (sequential liveness verified)
    ushort* s_h    = qkvh;
    ushort* s_l    = qkvl;
    float*  zlocal = (float*)vTh;          // 8 MB spanning vTh+vTl
    ushort* hffh   = (ushort*)score;
    ushort* h1b    = (ushort*)score;
    ushort* g1b    = (ushort*)score;
    ushort* g2b    = hffl;
    float*  ffnout = attn;
    float*  xrec   = attn;
    float*  quant  = zbuf;
    ushort* quantb = zh;

    float* out = (float*)d_out;
    float* loss_out = out + PSI_FLOATS;

    hipMemsetAsync(accd, 0, 3 * sizeof(double), stream);

    // ---- precompute: splits / transposed bf16 weights ----
    xsplit_kernel<<<1024, 256, 0, stream>>>(x, xh, xl);
    wtrans_kernel<1><<<dim3(4, 8), 256, 0, stream>>>(Wq_w, 256, 128, wqkvTh, wqkvTl, 0, 256);
    wtrans_kernel<1><<<dim3(4, 8), 256, 0, stream>>>(Wk_w, 256, 128, wqkvTh, wqkvTl, 128, 256);
    wtrans_kernel<1><<<dim3(8, 8), 256, 0, stream>>>(Wv_w, 256, 256, wqkvTh, wqkvTl, 256, 256);
    wtrans_kernel<1><<<dim3(32, 8), 256, 0, stream>>>(ffn_w1, 256, 1024, fw1Th, fw1Tl, 0, 256);
    wtrans_kernel<1><<<dim3(8, 32), 256, 0, stream>>>(ffn_w2, 1024, 256, fw2Th, fw2Tl, 0, 1024);
    wtrans_kernel<0><<<dim3(32, 8), 256, 0, stream>>>(li_w1, 256, 1024, liw1T, nullptr, 0, 256);
    wtrans_kernel<0><<<dim3(8, 32), 256, 0, stream>>>(li_w2, 1024, 256, liw2T, nullptr, 0, 1024);
    wtrans_kernel<0><<<dim3(32, 8), 256, 0, stream>>>(dec_w1, 256, 1024, decw1T, nullptr, 0, 256);
    wtrans_kernel<0><<<dim3(32, 32), 256, 0, stream>>>(dec_w2, 1024, 1024, decw2T, nullptr, 0, 1024);
    wtrans_kernel<0><<<dim3(8, 32), 256, 0, stream>>>(dec_w3, 1024, 256, decw3T, nullptr, 0, 1024);
    bias_concat_kernel<<<1, 512, 0, stream>>>(Wq_b, Wk_b, Wv_b, qkvbias);

    // ---- attention path (split-bf16, fp32-quality) ----
    // qkv fused: [8192,256] @ [512,256]^T -> qkv hi/lo [8192,512]
    gemm_mfma<128, 1, 0, 2><<<dim3(64, 4, 1), 256, 0, stream>>>(
        xh, xl, 0, 256, wqkvTh, wqkvTl, 0, 256, qkvbias,
        qkvh, qkvl, 0, 512, 256, 1.0f);
    vtrans_kernel<<<dim3(16, 8, 16), 256, 0, stream>>>(qkvh, qkvl, vTh, vTl);
    // scores = q @ k^T * 1/sqrt(128)
    gemm_mfma<128, 1, 0, 0><<<dim3(4, 4, 16), 256, 0, stream>>>(
        qkvh, qkvl, 262144, 512, qkvh + 128, qkvl + 128, 262144, 512, nullptr,
        score, nullptr, 262144, 512, 128, 0.08838834764831843f);
    softmax_split_kernel<<<2048, 256, 0, stream>>>(score, s_h, s_l);
    // attn = P @ V  (B = vT [256,512] per batch)
    gemm_mfma<64, 1, 0, 0><<<dim3(8, 2, 16), 256, 0, stream>>>(
        s_h, s_l, 262144, 512, vTh, vTl, 131072, 512, nullptr,
        attn, nullptr, 131072, 256, 512, 1.0f);
    ln_kernel<1><<<2048, 256, 0, stream>>>(x, attn, ln1_g, ln1_b, zbuf, zh, zl);
    // ffn
    gemm_mfma<128, 1, 1, 2><<<dim3(64, 8, 1), 256, 0, stream>>>(
        zh, zl, 0, 256, fw1Th, fw1Tl, 0, 256, ffn_b1,
        hffh, hffl, 0, 1024, 256, 1.0f);
    gemm_mfma<64, 1, 0, 0><<<dim3(128, 2, 1), 256, 0, stream>>>(
        hffh, hffl, 0, 1024, fw2Th, fw2Tl, 0, 1024, ffn_b2,
        ffnout, nullptr, 0, 256, 1024, 1.0f);
    ln_kernel<0><<<2048, 256, 0, stream>>>(zbuf, ffnout, ln2_g, ln2_b, zc, nullptr, nullptr);

    // ---- VQ ----
    vq_kernel<<<256, 256, 0, stream>>>(zc, emb, quant, quantb);

    // ---- local inference head (plain bf16; loss-only) ----
    gemm_mfma<128, 0, 1, 1><<<dim3(64, 8, 1), 256, 0, stream>>>(
        xh, nullptr, 0, 256, liw1T, nullptr, 0, 256, li_b1,
        h1b, nullptr, 0, 1024, 256, 1.0f);
    gemm_mfma<64, 0, 0, 0><<<dim3(128, 2, 1), 256, 0, stream>>>(
        h1b, nullptr, 0, 1024, liw2T, nullptr, 0, 1024, li_b2,
        zlocal, nullptr, 0, 256, 1024, 1.0f);

    // ---- decoder (plain bf16; loss-only) ----
    gemm_mfma<128, 0, 1, 1><<<dim3(64, 8, 1), 256, 0, stream>>>(
        quantb, nullptr, 0, 256, decw1T, nullptr, 0, 256, dec_b1,
        g1b, nullptr, 0, 1024, 256, 1.0f);
    gemm_mfma<128, 0, 1, 1><<<dim3(64, 8, 1), 256, 0, stream>>>(
        g1b, nullptr, 0, 1024, decw2T, nullptr, 0, 1024, dec_b2,
        g2b, nullptr, 0, 1024, 1024, 1.0f);
    gemm_mfma<64, 0, 0, 0><<<dim3(128, 2, 1), 256, 0, stream>>>(
        g2b, nullptr, 0, 1024, decw3T, nullptr, 0, 1024, dec_b3,
        xrec, nullptr, 0, 256, 1024, 1.0f);

    // ---- losses + psi ----
    loss_reduce_kernel<<<1024, 256, 0, stream>>>(xrec, x, quant, zc, zlocal, accd);
    finalize_loss_kernel<<<1, 64, 0, stream>>>(accd, loss_out);
    psi_fill_kernel<<<2048, 256, 0, stream>>>(zc, emb, (float4*)out);
}